// Round 2
// baseline (744.177 us; speedup 1.0000x reference)
//
#include <hip/hip_runtime.h>

// EHD layer: 3x3 x 8-orientation conv -> argmax+threshold -> 9-bin one-hot
// -> 5x5 box count / 25.  Fused single kernel, u64-packed 9x7-bit histograms.
// (Round 1: identical to round 0 — previous bench was an infra failure,
//  resubmitting to obtain the baseline measurement.)

#define BN   16
#define HH   1024
#define WW   1024
#define NOR  8
#define H2   1018   // output H (1024-2-4)
#define W2   1018   // output W
#define TH   16     // output tile rows per block
#define TW   64     // output tile cols per block
#define XH   (TH+6) // 22  x-tile rows
#define XW   (TW+6) // 70  x-tile cols
#define XWP  71     // padded
#define OHH  (TH+4) // 20  idx-tile rows
#define OHW  (TW+4) // 68  idx-tile cols
#define OHWP 69     // padded

__global__ __launch_bounds__(256)
void ehd_kernel(const float* __restrict__ x,
                const float* __restrict__ masks,
                float* __restrict__ out)
{
    __shared__ float xs[XH][XWP];
    __shared__ unsigned long long oh[OHH][OHWP];
    __shared__ unsigned long long rs[OHH][TW];

    const int tid = threadIdx.x;
    const int w0  = blockIdx.x * TW;
    const int h0  = blockIdx.y * TH;
    const int b   = blockIdx.z;

    // masks -> registers (uniform across threads, L1-cached)
    float m[NOR][9];
#pragma unroll
    for (int o = 0; o < NOR; ++o)
#pragma unroll
        for (int t = 0; t < 9; ++t)
            m[o][t] = masks[o * 9 + t];

    // ---- stage x tile (clamped at edges; clamped values only feed discarded outputs)
    const float* xb = x + (long)b * HH * WW;
    for (int t = tid; t < XH * XW; t += 256) {
        int i = t / XW, j = t - i * XW;
        int gh = h0 + i; if (gh > HH - 1) gh = HH - 1;
        int gw = w0 + j; if (gw > WW - 1) gw = WW - 1;
        xs[i][j] = xb[gh * WW + gw];
    }
    __syncthreads();

    // ---- conv -> argmax -> threshold -> packed one-hot (9 fields x 7 bits)
    for (int t = tid; t < OHH * OHW; t += 256) {
        int i = t / OHW, j = t - i * OHW;
        float xv[9];
#pragma unroll
        for (int di = 0; di < 3; ++di)
#pragma unroll
            for (int dj = 0; dj < 3; ++dj)
                xv[di * 3 + dj] = xs[i + di][j + dj];

        float best = 0.0f; int bi = 0;
#pragma unroll
        for (int o = 0; o < NOR; ++o) {
            float acc = xv[0] * m[o][0];
#pragma unroll
            for (int k = 1; k < 9; ++k)
                acc = fmaf(xv[k], m[o][k], acc);
            if (o == 0)          { best = acc; bi = 0; }
            else if (acc > best) { best = acc; bi = o; }   // strict > : first-max, matches jnp.argmax
        }
        if (best < 0.9f) bi = NOR;                         // 'no edge' bin
        oh[i][j] = 1ull << (7 * bi);
    }
    __syncthreads();

    // ---- horizontal 5-window sums (u64 packed adds)
    for (int t = tid; t < OHH * TW; t += 256) {
        int i = t / TW, j = t - i * TW;
        unsigned long long s = oh[i][j];
#pragma unroll
        for (int d = 1; d < 5; ++d) s += oh[i][j + d];
        rs[i][j] = s;
    }
    __syncthreads();

    // ---- vertical 5-window sums, extract 9 bins, store
    const int j  = tid & 63;
    const int i0 = tid >> 6;
    const int gw = w0 + j;
    for (int ii = i0; ii < TH; ii += 4) {
        const int gh = h0 + ii;
        unsigned long long s = rs[ii][j];
#pragma unroll
        for (int d = 1; d < 5; ++d) s += rs[ii + d][j];
        if (gh < H2 && gw < W2) {
#pragma unroll
            for (int k = 0; k < 9; ++k) {
                float c = (float)((unsigned)(s >> (7 * k)) & 0x7Fu);
                out[(((long)b * 9 + k) * H2 + gh) * W2 + gw] = c * (1.0f / 25.0f);
            }
        }
    }
}

extern "C" void kernel_launch(void* const* d_in, const int* in_sizes, int n_in,
                              void* d_out, int out_size, void* d_ws, size_t ws_size,
                              hipStream_t stream)
{
    const float* x     = (const float*)d_in[0];
    const float* masks = (const float*)d_in[1];
    float* out         = (float*)d_out;

    dim3 grid((W2 + TW - 1) / TW,   // 16
              (H2 + TH - 1) / TH,   // 64
              BN);                  // 16
    ehd_kernel<<<grid, 256, 0, stream>>>(x, masks, out);
}